// Round 5
// baseline (12243.777 us; speedup 1.0000x reference)
//
#include <hip/hip_runtime.h>
#include <hip/hip_bf16.h>

// Seq2seq LSTM (enc 1024 steps -> dec 1024 steps, reversed, proj-before-update).
// 16 WGs x 256 thr. 8 groups x 16 batches; 2 WGs/group each own 512 of the
// 1024 gate rows. f16 weight fragments persistent in VGPRs/AGPRs. Gates via
// mfma_f32_16x16x32_f16, K=320.
//
// R5 sync protocol: SELF-VALIDATING TAGGED PAYLOAD (no flags, no drains).
// Every exchanged 32-bit word = (tag<<16) | f16_payload, tag = consuming step
// (1..2047). Dword atomicity at the coherence point makes each word
// self-validating: producer just ISSUES tagged stores (never waits);
// consumer speculatively issues its tagged loads BEFORE its own-half MFMAs
// (latency hidden), then validates all 32 tags in-register and spin-reloads
// only if stale. Steady state: first check passes -> zero serial sync cost.
// Startup safety: tagged buffer initialized to sentinel tag 0xFFFF by prep.
// Only R1-proven primitives: relaxed agent-scope __hip_atomic_load/store.

#define Bb 128
#define Tt 1024
#define Ff 64
#define Hh 256

typedef _Float16 h16;
typedef __attribute__((ext_vector_type(8))) _Float16 h16x8;
typedef __attribute__((ext_vector_type(4))) float f32x4;
typedef unsigned long long u64;
typedef unsigned int u32;

// ws layout (f16 element offsets)
#define WENC_OFF 0          // 2*4*8*10*64*8 = 327680 f16
#define WDEC_OFF 327680
#define WOUT_OFF 655360     // 2*2*8*64*8 = 16384 f16
#define FLAGS_BYTE_OFF 1474560   // u32[256] (legacy, zeroed, unused in main)
#define TAGHB_BYTE_OFF 1475584   // u64[16 wg][2 slots][1024] tagged h, 256 KB

__device__ __forceinline__ float fast_sigmoid(float x) {
  float e = __expf(-fabsf(x));
  float s = __builtin_amdgcn_rcpf(1.f + e);
  return x >= 0.f ? s : 1.f - s;
}
__device__ __forceinline__ float fast_tanh(float x) {
  float e = __expf(-2.f * fabsf(x));
  float r = (1.f - e) * __builtin_amdgcn_rcpf(1.f + e);
  return x >= 0.f ? r : -r;
}
__device__ __forceinline__ h16x8 pack16(u64 lo, u64 hi) {
  union { u64 u[2]; h16x8 v; } x;
  x.u[0] = lo; x.u[1] = hi;
  return x.v;
}
// rebuild one untagged u64 (4 f16) from two tagged u64 (4 tagged words)
__device__ __forceinline__ u64 detag2(u64 p, u64 q) {
  u32 w0 = (u32)p, w1 = (u32)(p >> 32), w2 = (u32)q, w3 = (u32)(q >> 32);
  u32 lo = (w0 & 0xFFFFu) | (w1 << 16);
  u32 hi = (w2 & 0xFFFFu) | (w3 << 16);
  return (u64)lo | ((u64)hi << 32);
}

// ---- prep: convert fp32 weights into f16 MFMA-fragment-ordered regions ----
__global__ void lstm_prep(const float* __restrict__ Wih_e, const float* __restrict__ Whh_e,
                          const float* __restrict__ Wih_d, const float* __restrict__ Whh_d,
                          const float* __restrict__ Wout, h16* __restrict__ ws16,
                          unsigned int* __restrict__ flags) {
  int e = blockIdx.x * 256 + threadIdx.x;
  if (e < 256) flags[e] = 0u;
  // tagged h buffer -> sentinel tag 0xFFFF (not in valid tag range 1..2047)
  if (e < 65536) {
    u32* tag32 = flags + 256;   // FLAGS_BYTE_OFF + 1024 = TAGHB_BYTE_OFF
    tag32[e] = 0xFFFF0000u;
  }
  if (e < 655360) {
    int r = e;
    const float* Wih = Wih_e; const float* Whh = Whh_e;
    int off = WENC_OFF;
    if (r >= 327680) { r -= 327680; Wih = Wih_d; Whh = Whh_d; off = WDEC_OFF; }
    // r = ((((q*4+w)*8+nt)*10+kt)*64+lane)*8 + j
    int j    = r & 7;
    int lane = (r >> 3) & 63;
    int kt   = (r >> 9) % 10;
    int tmp  = (r >> 9) / 10;        // (q*4+w)*8+nt
    int nt   = tmp & 7;
    int w    = (tmp >> 3) & 3;
    int q    = tmp >> 5;
    int g = nt >> 1, ct = nt & 1;
    int col = q * 128 + w * 32 + ct * 16 + (lane & 15);
    int row = g * 256 + col;
    int k = kt * 32 + (lane >> 4) * 8 + j;
    float v = (k < 64) ? Wih[row * 64 + k] : Whh[row * 256 + (k - 64)];
    ws16[off + r] = (h16)v;
  } else if (e < 655360 + 16384) {
    int r = e - 655360;
    // r = (((q*2+wt)*8+kt)*64+lane)*8 + j
    int j    = r & 7;
    int lane = (r >> 3) & 63;
    int kt   = (r >> 9) & 7;
    int wt   = (r >> 12) & 1;
    int q    = (r >> 13) & 1;
    int f = q * 32 + wt * 16 + (lane & 15);
    int k = kt * 32 + (lane >> 4) * 8 + j;
    ws16[WOUT_OFF + r] = (h16)Wout[f * 256 + k];
  }
}

#define MFMA_KT(kt) do {                                                         \
    acc[0] = __builtin_amdgcn_mfma_f32_16x16x32_f16(a[kt], wf[0][kt], acc[0], 0, 0, 0); \
    acc[1] = __builtin_amdgcn_mfma_f32_16x16x32_f16(a[kt], wf[1][kt], acc[1], 0, 0, 0); \
    acc[2] = __builtin_amdgcn_mfma_f32_16x16x32_f16(a[kt], wf[2][kt], acc[2], 0, 0, 0); \
    acc[3] = __builtin_amdgcn_mfma_f32_16x16x32_f16(a[kt], wf[3][kt], acc[3], 0, 0, 0); \
    acc[4] = __builtin_amdgcn_mfma_f32_16x16x32_f16(a[kt], wf[4][kt], acc[4], 0, 0, 0); \
    acc[5] = __builtin_amdgcn_mfma_f32_16x16x32_f16(a[kt], wf[5][kt], acc[5], 0, 0, 0); \
    acc[6] = __builtin_amdgcn_mfma_f32_16x16x32_f16(a[kt], wf[6][kt], acc[6], 0, 0, 0); \
    acc[7] = __builtin_amdgcn_mfma_f32_16x16x32_f16(a[kt], wf[7][kt], acc[7], 0, 0, 0); \
  } while (0)

#define LOAD16() do {                                                            \
    _Pragma("unroll")                                                            \
    for (int ii = 0; ii < 8; ++ii) {                                             \
      const int bi = 2 * (jb + OFFS[ii]);                                        \
      tg[2 * ii]     = __hip_atomic_load(tb + bi,     __ATOMIC_RELAXED,          \
                                         __HIP_MEMORY_SCOPE_AGENT);              \
      tg[2 * ii + 1] = __hip_atomic_load(tb + bi + 1, __ATOMIC_RELAXED,          \
                                         __HIP_MEMORY_SCOPE_AGENT);              \
    }                                                                            \
  } while (0)

// ---- main persistent kernel ----
__global__ __launch_bounds__(256, 1) void lstm_main(
    const float* __restrict__ ts,
    const float* __restrict__ b_enc, const float* __restrict__ b_dec,
    const float* __restrict__ b_out,
    const h16* __restrict__ wsW, u64* __restrict__ tagbuf,
    float* __restrict__ out) {
  const int tid = threadIdx.x;
  const int wg = blockIdx.x;
  const int grp = wg & 7, q = wg >> 3;
  const int w = tid >> 6, lane = tid & 63;
  const int n16 = lane & 15, quad = lane >> 4;
  const int b0 = grp * 16;
  const int partner = wg ^ 8;

  __shared__ __align__(16) h16 xh[2][16][328];  // k: 0..63 x, 64..319 h
  __shared__ h16x8 woutLds[1024];               // 32-f slice of W_out frags

  // persistent weight fragments: 8 N-tiles x 10 K-tiles
  h16x8 wf[8][10];
  {
    const h16x8* wsrc = (const h16x8*)(wsW + WENC_OFF);
#pragma unroll
    for (int nt = 0; nt < 8; ++nt)
#pragma unroll
      for (int kt = 0; kt < 10; ++kt)
        wf[nt][kt] = wsrc[(((q * 4 + w) * 8 + nt) * 10 + kt) * 64 + lane];
  }
  float bias8[8];
#pragma unroll
  for (int nt = 0; nt < 8; ++nt) {
    int g = nt >> 1, ct = nt & 1;
    bias8[nt] = b_enc[g * 256 + q * 128 + w * 32 + ct * 16 + n16];
  }
  const float bo = b_out[q * 32 + w * 16 + n16];

  float c8[8];
#pragma unroll
  for (int i = 0; i < 8; ++i) c8[i] = 0.f;

  // zero h-region of xh[0]; stage x_0
  for (int i = tid; i < 16 * 264; i += 256) {
    int m = i / 264;
    xh[0][m][64 + (i - m * 264)] = (h16)0.f;
  }
  const int m_x = tid >> 4, ks_x = (tid & 15) * 4;
  {
    const f32x4 xv0 = *(const f32x4*)(ts + ((size_t)(b0 + m_x) * Tt + 0) * Ff + ks_x);
#pragma unroll
    for (int u = 0; u < 4; ++u) xh[0][m_x][ks_x + u] = (h16)xv0[u];
  }
  __syncthreads();

  static const int OFFS[8] = {0, 1, 8, 9, 16, 17, 24, 25};
  const int jb = (n16 * 16 + quad) * 2;

  for (int t = 0; t < 2048; ++t) {
    const int nb = t & 1, nxt = nb ^ 1;
    const bool dec = (t >= 1024);

    // phase switch: decoder weights + biases + W_out -> LDS (once)
    if (t == 1024) {
      const h16x8* wsrc2 = (const h16x8*)(wsW + WDEC_OFF);
#pragma unroll
      for (int nt = 0; nt < 8; ++nt)
#pragma unroll
        for (int kt = 0; kt < 10; ++kt)
          wf[nt][kt] = wsrc2[(((q * 4 + w) * 8 + nt) * 10 + kt) * 64 + lane];
#pragma unroll
      for (int nt = 0; nt < 8; ++nt) {
        int g = nt >> 1, ct = nt & 1;
        bias8[nt] = b_dec[g * 256 + q * 128 + w * 32 + ct * 16 + n16];
      }
      const h16x8* wo = (const h16x8*)(wsW + WOUT_OFF) + q * 1024;
      for (int i = tid; i < 1024; i += 256) woutLds[i] = wo[i];
      __syncthreads();
    }

    // (a) partner-independent A-fragments: x + own h-half from LDS
    h16x8 a[10];
    const h16* xrow = &xh[nb][n16][0];
    a[0] = *(const h16x8*)(xrow + 0 * 32 + quad * 8);
    a[1] = *(const h16x8*)(xrow + 1 * 32 + quad * 8);
    if (q == 0) {
      a[2] = *(const h16x8*)(xrow + 2 * 32 + quad * 8);
      a[3] = *(const h16x8*)(xrow + 3 * 32 + quad * 8);
      a[4] = *(const h16x8*)(xrow + 4 * 32 + quad * 8);
      a[5] = *(const h16x8*)(xrow + 5 * 32 + quad * 8);
    } else {
      a[6] = *(const h16x8*)(xrow + 6 * 32 + quad * 8);
      a[7] = *(const h16x8*)(xrow + 7 * 32 + quad * 8);
      a[8] = *(const h16x8*)(xrow + 8 * 32 + quad * 8);
      a[9] = *(const h16x8*)(xrow + 9 * 32 + quad * 8);
    }

    // (spec) speculatively issue the 16 tagged partner-h loads; their latency
    // hides under the 48 own-half MFMAs below. Tags validated after.
    const u64* tb = tagbuf + ((size_t)partner * 2 + nxt) * 1024;
    u64 tg[16];
    if (t > 0) LOAD16();

    // (b) bias init + own-part MFMAs (48)
    f32x4 acc[8];
#pragma unroll
    for (int nt = 0; nt < 8; ++nt) {
      f32x4 v; v[0] = bias8[nt]; v[1] = bias8[nt]; v[2] = bias8[nt]; v[3] = bias8[nt];
      acc[nt] = v;
    }
    MFMA_KT(0); MFMA_KT(1);
    if (q == 0) { MFMA_KT(2); MFMA_KT(3); MFMA_KT(4); MFMA_KT(5); }
    else        { MFMA_KT(6); MFMA_KT(7); MFMA_KT(8); MFMA_KT(9); }

    // (c) prefetch x for step t+1
    f32x4 xv;
#pragma unroll
    for (int u = 0; u < 4; ++u) xv[u] = 0.f;
    if (t + 1 < 2048) {
      int xi = (t + 1 < 1024) ? (t + 1) : (2047 - (t + 1));
      xv = *(const f32x4*)(ts + ((size_t)(b0 + m_x) * Tt + xi) * Ff + ks_x);
    }

    // (d) validate tags (= t); spin-reload only if stale; detag; 32 MFMAs
    if (t > 0) {
      const u64 tmask = 0xFFFF0000FFFF0000ull;
      const u64 texp = ((u64)(u32)t << 48) | ((u64)(u32)t << 16);
      for (;;) {
        bool ok = true;
#pragma unroll
        for (int ii = 0; ii < 16; ++ii) ok &= ((tg[ii] & tmask) == texp);
        if (ok) break;
        LOAD16();
      }
      u64 d0 = detag2(tg[0],  tg[1]);
      u64 d1 = detag2(tg[2],  tg[3]);
      u64 d2 = detag2(tg[4],  tg[5]);
      u64 d3 = detag2(tg[6],  tg[7]);
      u64 d4 = detag2(tg[8],  tg[9]);
      u64 d5 = detag2(tg[10], tg[11]);
      u64 d6 = detag2(tg[12], tg[13]);
      u64 d7 = detag2(tg[14], tg[15]);
      if (q == 0) {
        a[6] = pack16(d0, d1); a[7] = pack16(d2, d3);
        a[8] = pack16(d4, d5); a[9] = pack16(d6, d7);
        MFMA_KT(6); MFMA_KT(7); MFMA_KT(8); MFMA_KT(9);
      } else {
        a[2] = pack16(d0, d1); a[3] = pack16(d2, d3);
        a[4] = pack16(d4, d5); a[5] = pack16(d6, d7);
        MFMA_KT(2); MFMA_KT(3); MFMA_KT(4); MFMA_KT(5);
      }
    }

    // (g) pointwise LSTM cell (fp32 c in regs)
    h16 hv[8];
#pragma unroll
    for (int ct = 0; ct < 2; ++ct)
#pragma unroll
      for (int r = 0; r < 4; ++r) {
        float i_ = fast_sigmoid(acc[0 + ct][r]);
        float f_ = fast_sigmoid(acc[2 + ct][r]);
        float g_ = fast_tanh(acc[4 + ct][r]);
        float o_ = fast_sigmoid(acc[6 + ct][r]);
        float cv = f_ * c8[ct * 4 + r] + i_ * g_;
        c8[ct * 4 + r] = cv;
        hv[ct * 4 + r] = (h16)(o_ * fast_tanh(cv));
      }

    // (h1) write h -> xh[nxt] own half; stage x_{t+1}
#pragma unroll
    for (int ct = 0; ct < 2; ++ct)
#pragma unroll
      for (int r = 0; r < 4; ++r) {
        int m = quad * 4 + r;
        int colLocal = w * 32 + ct * 16 + n16;
        xh[nxt][m][64 + q * 128 + colLocal] = hv[ct * 4 + r];
      }
    if (t + 1 < 2048) {
#pragma unroll
      for (int u = 0; u < 4; ++u) xh[nxt][m_x][ks_x + u] = (h16)xv[u];
    }

    // (h2) barrier: xh[nxt] h-region complete across all waves
    __syncthreads();

    // (pub) publish own h-half as tagged words (tag = t+1 = consuming step).
    // Pure store issue -- no drain, no flag, nothing to wait on.
    if (t < 2047) {
      u64* pb = tagbuf + ((size_t)wg * 2 + nb) * 1024;
      const u32 tagw = (u32)(t + 1) << 16;
#pragma unroll
      for (int r2 = 0; r2 < 2; ++r2) {
        const int k = tid + r2 * 256;
        u64 v = *(const u64*)(&xh[nxt][k >> 5][64 + q * 128 + (k & 31) * 4]);
        u32 lo = (u32)v, hi = (u32)(v >> 32);
        u64 tglo = (u64)(tagw | (lo & 0xFFFFu)) | ((u64)(tagw | (lo >> 16)) << 32);
        u64 tghi = (u64)(tagw | (hi & 0xFFFFu)) | ((u64)(tagw | (hi >> 16)) << 32);
        __hip_atomic_store(pb + 2 * k,     tglo, __ATOMIC_RELAXED, __HIP_MEMORY_SCOPE_AGENT);
        __hip_atomic_store(pb + 2 * k + 1, tghi, __ATOMIC_RELAXED, __HIP_MEMORY_SCOPE_AGENT);
      }
    }

    // (h5) decoder output projection (PRE-update h = a[2..9]) -- after publish
    if (dec && w < 2) {
      f32x4 ao; ao[0] = bo; ao[1] = bo; ao[2] = bo; ao[3] = bo;
#pragma unroll
      for (int kt = 0; kt < 8; ++kt)
        ao = __builtin_amdgcn_mfma_f32_16x16x32_f16(a[2 + kt], woutLds[(w * 8 + kt) * 64 + lane], ao, 0, 0, 0);
      int tpos = 2047 - t;
      int f = q * 32 + w * 16 + n16;
#pragma unroll
      for (int r = 0; r < 4; ++r) {
        int m = quad * 4 + r;
        out[((size_t)(b0 + m) * Tt + tpos) * Ff + f] = ao[r];
      }
    }
  }
}

extern "C" void kernel_launch(void* const* d_in, const int* in_sizes, int n_in,
                              void* d_out, int out_size, void* d_ws, size_t ws_size,
                              hipStream_t stream) {
  const float* ts  = (const float*)d_in[0];
  const float* Wie = (const float*)d_in[1];
  const float* Whe = (const float*)d_in[2];
  const float* be  = (const float*)d_in[3];
  const float* Wid = (const float*)d_in[4];
  const float* Whd = (const float*)d_in[5];
  const float* bd  = (const float*)d_in[6];
  const float* Wo  = (const float*)d_in[7];
  const float* bo  = (const float*)d_in[8];

  h16* ws16 = (h16*)d_ws;
  unsigned int* flags = (unsigned int*)((char*)d_ws + FLAGS_BYTE_OFF);
  u64* tagbuf = (u64*)((char*)d_ws + TAGHB_BYTE_OFF);
  float* out = (float*)d_out;

  // total ws use: ~1.47 MB + 256 KB tagged h = ~1.74 MB
  lstm_prep<<<2624, 256, 0, stream>>>(Wie, Whe, Wid, Whd, Wo, ws16, flags);
  lstm_main<<<16, 256, 0, stream>>>(ts, be, bd, bo, ws16, tagbuf, out);
}

// Round 6
// 9581.303 us; speedup vs baseline: 1.2779x; 1.2779x over previous
//
#include <hip/hip_runtime.h>
#include <hip/hip_bf16.h>

// Seq2seq LSTM (enc 1024 steps -> dec 1024 steps, reversed, proj-before-update).
// 16 WGs x 256 thr. 8 groups x 16 batches; 2 WGs/group each own 512 of the
// 1024 gate rows. f16 weight fragments persistent in VGPRs/AGPRs. Gates via
// mfma_f32_16x16x32_f16, K=320.
//
// R6 sync protocol: TIERED TAGGED EXCHANGE. No flags, no drains, no probes.
//  * Producer publishes h as tagged words ((tag<<16)|f16, tag = consuming
//    step) with sc0 sc1 STORES -> write-through: guaranteed visible at the
//    IC (liveness anchor); if the pair shares an XCD L2 a fresh copy is
//    serviceable there. Fire-and-forget.
//  * Consumer (after its partner-independent MFMAs): round 0,1 = sc0 loads
//    (L1-bypass, L2-hit fast path if co-XCD); on stale tags, every other
//    round escalates to sc0 sc1 (IC) -> always eventually fresh, so the
//    protocol is live under ANY workgroup->XCD mapping and any cache
//    allocation policy. Tags make staleness detectable, never silent.
//  * 2-slot buffers; generation safety by the same induction as R1.
// Lesson from R5 applied: loads are NOT issued speculatively at step start
// (data can't be there yet); they issue right after the own-half MFMAs.

#define Bb 128
#define Tt 1024
#define Ff 64
#define Hh 256

typedef _Float16 h16;
typedef __attribute__((ext_vector_type(8))) _Float16 h16x8;
typedef __attribute__((ext_vector_type(4))) float f32x4;
typedef __attribute__((ext_vector_type(4))) unsigned int u32x4;
typedef unsigned long long u64;
typedef unsigned int u32;

// ws layout (f16 element offsets)
#define WENC_OFF 0          // 2*4*8*10*64*8 = 327680 f16
#define WDEC_OFF 327680
#define WOUT_OFF 655360     // 2*2*8*64*8 = 16384 f16
#define FLAGS_BYTE_OFF 1474560   // u32[256] legacy (zeroed, unused in main)
#define TAGHB_BYTE_OFF 1475584   // u64[16 wg][2 slots][1024] tagged h, 256 KB

__device__ __forceinline__ float fast_sigmoid(float x) {
  float e = __expf(-fabsf(x));
  float s = __builtin_amdgcn_rcpf(1.f + e);
  return x >= 0.f ? s : 1.f - s;
}
__device__ __forceinline__ float fast_tanh(float x) {
  float e = __expf(-2.f * fabsf(x));
  float r = (1.f - e) * __builtin_amdgcn_rcpf(1.f + e);
  return x >= 0.f ? r : -r;
}
__device__ __forceinline__ h16x8 pack16(u64 lo, u64 hi) {
  union { u64 u[2]; h16x8 v; } x;
  x.u[0] = lo; x.u[1] = hi;
  return x.v;
}
// one payload u64 (4 f16) from one tagged 16B group (4 tagged words)
__device__ __forceinline__ u64 detag4(u32x4 g) {
  u32 lo = (g[0] & 0xFFFFu) | (g[1] << 16);
  u32 hi = (g[2] & 0xFFFFu) | (g[3] << 16);
  return (u64)lo | ((u64)hi << 32);
}

// ---- prep: convert fp32 weights into f16 MFMA-fragment-ordered regions ----
__global__ void lstm_prep(const float* __restrict__ Wih_e, const float* __restrict__ Whh_e,
                          const float* __restrict__ Wih_d, const float* __restrict__ Whh_d,
                          const float* __restrict__ Wout, h16* __restrict__ ws16,
                          unsigned int* __restrict__ flags) {
  int e = blockIdx.x * 256 + threadIdx.x;
  if (e < 256) flags[e] = 0u;
  // tagged h buffer -> sentinel tag 0xFFFF (not in valid tag range 1..2047)
  if (e < 65536) {
    u32* tag32 = flags + 256;   // FLAGS_BYTE_OFF + 1024 = TAGHB_BYTE_OFF
    tag32[e] = 0xFFFF0000u;
  }
  if (e < 655360) {
    int r = e;
    const float* Wih = Wih_e; const float* Whh = Whh_e;
    int off = WENC_OFF;
    if (r >= 327680) { r -= 327680; Wih = Wih_d; Whh = Whh_d; off = WDEC_OFF; }
    // r = ((((q*4+w)*8+nt)*10+kt)*64+lane)*8 + j
    int j    = r & 7;
    int lane = (r >> 3) & 63;
    int kt   = (r >> 9) % 10;
    int tmp  = (r >> 9) / 10;        // (q*4+w)*8+nt
    int nt   = tmp & 7;
    int w    = (tmp >> 3) & 3;
    int q    = tmp >> 5;
    int g = nt >> 1, ct = nt & 1;
    int col = q * 128 + w * 32 + ct * 16 + (lane & 15);
    int row = g * 256 + col;
    int k = kt * 32 + (lane >> 4) * 8 + j;
    float v = (k < 64) ? Wih[row * 64 + k] : Whh[row * 256 + (k - 64)];
    ws16[off + r] = (h16)v;
  } else if (e < 655360 + 16384) {
    int r = e - 655360;
    // r = (((q*2+wt)*8+kt)*64+lane)*8 + j
    int j    = r & 7;
    int lane = (r >> 3) & 63;
    int kt   = (r >> 9) & 7;
    int wt   = (r >> 12) & 1;
    int q    = (r >> 13) & 1;
    int f = q * 32 + wt * 16 + (lane & 15);
    int k = kt * 32 + (lane >> 4) * 8 + j;
    ws16[WOUT_OFF + r] = (h16)Wout[f * 256 + k];
  }
}

#define MFMA_KT(kt) do {                                                         \
    acc[0] = __builtin_amdgcn_mfma_f32_16x16x32_f16(a[kt], wf[0][kt], acc[0], 0, 0, 0); \
    acc[1] = __builtin_amdgcn_mfma_f32_16x16x32_f16(a[kt], wf[1][kt], acc[1], 0, 0, 0); \
    acc[2] = __builtin_amdgcn_mfma_f32_16x16x32_f16(a[kt], wf[2][kt], acc[2], 0, 0, 0); \
    acc[3] = __builtin_amdgcn_mfma_f32_16x16x32_f16(a[kt], wf[3][kt], acc[3], 0, 0, 0); \
    acc[4] = __builtin_amdgcn_mfma_f32_16x16x32_f16(a[kt], wf[4][kt], acc[4], 0, 0, 0); \
    acc[5] = __builtin_amdgcn_mfma_f32_16x16x32_f16(a[kt], wf[5][kt], acc[5], 0, 0, 0); \
    acc[6] = __builtin_amdgcn_mfma_f32_16x16x32_f16(a[kt], wf[6][kt], acc[6], 0, 0, 0); \
    acc[7] = __builtin_amdgcn_mfma_f32_16x16x32_f16(a[kt], wf[7][kt], acc[7], 0, 0, 0); \
  } while (0)

// one tagged-load round: 8 x dwordx4 (32 tagged words = full partner frag set)
#define LOADRND(SC) do {                                                         \
    asm volatile(                                                                \
        "global_load_dwordx4 %0, %8, off " SC "\n\t"                             \
        "global_load_dwordx4 %1, %8, off offset:16 " SC "\n\t"                   \
        "global_load_dwordx4 %2, %8, off offset:128 " SC "\n\t"                  \
        "global_load_dwordx4 %3, %8, off offset:144 " SC "\n\t"                  \
        "global_load_dwordx4 %4, %8, off offset:256 " SC "\n\t"                  \
        "global_load_dwordx4 %5, %8, off offset:272 " SC "\n\t"                  \
        "global_load_dwordx4 %6, %8, off offset:384 " SC "\n\t"                  \
        "global_load_dwordx4 %7, %8, off offset:400 " SC "\n\t"                  \
        "s_waitcnt vmcnt(0)"                                                     \
        : "=&v"(g0), "=&v"(g1), "=&v"(g2), "=&v"(g3),                            \
          "=&v"(g4), "=&v"(g5), "=&v"(g6), "=&v"(g7)                             \
        : "v"(tbp)                                                               \
        : "memory");                                                             \
  } while (0)

// ---- main persistent kernel ----
__global__ __launch_bounds__(256, 1) void lstm_main(
    const float* __restrict__ ts,
    const float* __restrict__ b_enc, const float* __restrict__ b_dec,
    const float* __restrict__ b_out,
    const h16* __restrict__ wsW, u64* __restrict__ tagbuf,
    float* __restrict__ out) {
  const int tid = threadIdx.x;
  const int wg = blockIdx.x;
  const int grp = wg & 7, q = wg >> 3;
  const int w = tid >> 6, lane = tid & 63;
  const int n16 = lane & 15, quad = lane >> 4;
  const int b0 = grp * 16;
  const int partner = wg ^ 8;

  __shared__ __align__(16) h16 xh[2][16][328];  // k: 0..63 x, 64..319 h
  __shared__ h16x8 woutLds[1024];               // 32-f slice of W_out frags

  // persistent weight fragments: 8 N-tiles x 10 K-tiles
  h16x8 wf[8][10];
  {
    const h16x8* wsrc = (const h16x8*)(wsW + WENC_OFF);
#pragma unroll
    for (int nt = 0; nt < 8; ++nt)
#pragma unroll
      for (int kt = 0; kt < 10; ++kt)
        wf[nt][kt] = wsrc[(((q * 4 + w) * 8 + nt) * 10 + kt) * 64 + lane];
  }
  float bias8[8];
#pragma unroll
  for (int nt = 0; nt < 8; ++nt) {
    int g = nt >> 1, ct = nt & 1;
    bias8[nt] = b_enc[g * 256 + q * 128 + w * 32 + ct * 16 + n16];
  }
  const float bo = b_out[q * 32 + w * 16 + n16];

  float c8[8];
#pragma unroll
  for (int i = 0; i < 8; ++i) c8[i] = 0.f;

  // zero h-region of xh[0]; stage x_0
  for (int i = tid; i < 16 * 264; i += 256) {
    int m = i / 264;
    xh[0][m][64 + (i - m * 264)] = (h16)0.f;
  }
  const int m_x = tid >> 4, ks_x = (tid & 15) * 4;
  {
    const f32x4 xv0 = *(const f32x4*)(ts + ((size_t)(b0 + m_x) * Tt + 0) * Ff + ks_x);
#pragma unroll
    for (int u = 0; u < 4; ++u) xh[0][m_x][ks_x + u] = (h16)xv0[u];
  }
  __syncthreads();

  const int jb = (n16 * 16 + quad) * 2;   // payload u64 index of this lane's frags

  for (int t = 0; t < 2048; ++t) {
    const int nb = t & 1, nxt = nb ^ 1;
    const bool dec = (t >= 1024);

    // phase switch: decoder weights + biases + W_out -> LDS (once)
    if (t == 1024) {
      const h16x8* wsrc2 = (const h16x8*)(wsW + WDEC_OFF);
#pragma unroll
      for (int nt = 0; nt < 8; ++nt)
#pragma unroll
        for (int kt = 0; kt < 10; ++kt)
          wf[nt][kt] = wsrc2[(((q * 4 + w) * 8 + nt) * 10 + kt) * 64 + lane];
#pragma unroll
      for (int nt = 0; nt < 8; ++nt) {
        int g = nt >> 1, ct = nt & 1;
        bias8[nt] = b_dec[g * 256 + q * 128 + w * 32 + ct * 16 + n16];
      }
      const h16x8* wo = (const h16x8*)(wsW + WOUT_OFF) + q * 1024;
      for (int i = tid; i < 1024; i += 256) woutLds[i] = wo[i];
      __syncthreads();
    }

    // (a) partner-independent A-fragments: x + own h-half from LDS
    h16x8 a[10];
    const h16* xrow = &xh[nb][n16][0];
    a[0] = *(const h16x8*)(xrow + 0 * 32 + quad * 8);
    a[1] = *(const h16x8*)(xrow + 1 * 32 + quad * 8);
    if (q == 0) {
      a[2] = *(const h16x8*)(xrow + 2 * 32 + quad * 8);
      a[3] = *(const h16x8*)(xrow + 3 * 32 + quad * 8);
      a[4] = *(const h16x8*)(xrow + 4 * 32 + quad * 8);
      a[5] = *(const h16x8*)(xrow + 5 * 32 + quad * 8);
    } else {
      a[6] = *(const h16x8*)(xrow + 6 * 32 + quad * 8);
      a[7] = *(const h16x8*)(xrow + 7 * 32 + quad * 8);
      a[8] = *(const h16x8*)(xrow + 8 * 32 + quad * 8);
      a[9] = *(const h16x8*)(xrow + 9 * 32 + quad * 8);
    }

    // (c) prefetch x for step t+1 -- issued early, consumed at (h1)
    f32x4 xv;
#pragma unroll
    for (int u = 0; u < 4; ++u) xv[u] = 0.f;
    if (t + 1 < 2048) {
      int xi = (t + 1 < 1024) ? (t + 1) : (2047 - (t + 1));
      xv = *(const f32x4*)(ts + ((size_t)(b0 + m_x) * Tt + xi) * Ff + ks_x);
    }

    // (b) bias init + own-part MFMAs (48)
    f32x4 acc[8];
#pragma unroll
    for (int nt = 0; nt < 8; ++nt) {
      f32x4 v; v[0] = bias8[nt]; v[1] = bias8[nt]; v[2] = bias8[nt]; v[3] = bias8[nt];
      acc[nt] = v;
    }
    MFMA_KT(0); MFMA_KT(1);
    if (q == 0) { MFMA_KT(2); MFMA_KT(3); MFMA_KT(4); MFMA_KT(5); }
    else        { MFMA_KT(6); MFMA_KT(7); MFMA_KT(8); MFMA_KT(9); }

    // (d) tiered tagged partner-h load: sc0 first (L2 fast path), escalate
    // every other round to sc0 sc1 (IC, guaranteed-fresh -> always live).
    if (t > 0) {
      const char* tbp = (const char*)(tagbuf + ((size_t)partner * 2 + nxt) * 1024)
                        + (size_t)jb * 16;
      u32x4 g0, g1, g2, g3, g4, g5, g6, g7;
      const u32 tgt = (u32)t;
      int round = 0;
      for (;;) {
        if (round >= 2 && (round & 1) == 0) { LOADRND("sc0 sc1"); }
        else                                { LOADRND("sc0"); }
        u32 bad = 0u;
#pragma unroll
        for (int j = 0; j < 4; ++j) {
          bad |= (g0[j] >> 16) ^ tgt; bad |= (g1[j] >> 16) ^ tgt;
          bad |= (g2[j] >> 16) ^ tgt; bad |= (g3[j] >> 16) ^ tgt;
          bad |= (g4[j] >> 16) ^ tgt; bad |= (g5[j] >> 16) ^ tgt;
          bad |= (g6[j] >> 16) ^ tgt; bad |= (g7[j] >> 16) ^ tgt;
        }
        if (bad == 0u) break;
        ++round;
      }
      u64 d0 = detag4(g0), d1 = detag4(g1), d2 = detag4(g2), d3 = detag4(g3);
      u64 d4 = detag4(g4), d5 = detag4(g5), d6 = detag4(g6), d7 = detag4(g7);
      if (q == 0) {
        a[6] = pack16(d0, d1); a[7] = pack16(d2, d3);
        a[8] = pack16(d4, d5); a[9] = pack16(d6, d7);
        MFMA_KT(6); MFMA_KT(7); MFMA_KT(8); MFMA_KT(9);
      } else {
        a[2] = pack16(d0, d1); a[3] = pack16(d2, d3);
        a[4] = pack16(d4, d5); a[5] = pack16(d6, d7);
        MFMA_KT(2); MFMA_KT(3); MFMA_KT(4); MFMA_KT(5);
      }
    }

    // (g) pointwise LSTM cell (fp32 c in regs)
    h16 hv[8];
#pragma unroll
    for (int ct = 0; ct < 2; ++ct)
#pragma unroll
      for (int r = 0; r < 4; ++r) {
        float i_ = fast_sigmoid(acc[0 + ct][r]);
        float f_ = fast_sigmoid(acc[2 + ct][r]);
        float g_ = fast_tanh(acc[4 + ct][r]);
        float o_ = fast_sigmoid(acc[6 + ct][r]);
        float cv = f_ * c8[ct * 4 + r] + i_ * g_;
        c8[ct * 4 + r] = cv;
        hv[ct * 4 + r] = (h16)(o_ * fast_tanh(cv));
      }

    // (h1) write h -> xh[nxt] own half; stage x_{t+1}
#pragma unroll
    for (int ct = 0; ct < 2; ++ct)
#pragma unroll
      for (int r = 0; r < 4; ++r) {
        int m = quad * 4 + r;
        int colLocal = w * 32 + ct * 16 + n16;
        xh[nxt][m][64 + q * 128 + colLocal] = hv[ct * 4 + r];
      }
    if (t + 1 < 2048) {
#pragma unroll
      for (int u = 0; u < 4; ++u) xh[nxt][m_x][ks_x + u] = (h16)xv[u];
    }

    // (h2) barrier: xh[nxt] h-region complete across all waves
    __syncthreads();

    // (pub) publish own h-half as tagged words, sc0 sc1 write-through
    // (visible at IC = liveness anchor; fresh L2 copy for a co-XCD partner).
    // Fire-and-forget: no drain, no flag.
    if (t < 2047) {
      const u32 tagw = (u32)(t + 1) << 16;
      const char* pbb = (const char*)(tagbuf + ((size_t)wg * 2 + nb) * 1024);
      u64 v0 = *(const u64*)(&xh[nxt][tid >> 5][64 + q * 128 + (tid & 31) * 4]);
      u64 v1 = *(const u64*)(&xh[nxt][(tid + 256) >> 5][64 + q * 128 + (tid & 31) * 4]);
      u32x4 s0, s1;
      {
        u32 lo = (u32)v0, hi = (u32)(v0 >> 32);
        s0[0] = tagw | (lo & 0xFFFFu); s0[1] = tagw | (lo >> 16);
        s0[2] = tagw | (hi & 0xFFFFu); s0[3] = tagw | (hi >> 16);
      }
      {
        u32 lo = (u32)v1, hi = (u32)(v1 >> 32);
        s1[0] = tagw | (lo & 0xFFFFu); s1[1] = tagw | (lo >> 16);
        s1[2] = tagw | (hi & 0xFFFFu); s1[3] = tagw | (hi >> 16);
      }
      const char* p0 = pbb + (size_t)tid * 16;
      const char* p1 = pbb + (size_t)(tid + 256) * 16;
      asm volatile(
          "global_store_dwordx4 %0, %2, off sc0 sc1\n\t"
          "global_store_dwordx4 %1, %3, off sc0 sc1"
          :: "v"(p0), "v"(p1), "v"(s0), "v"(s1)
          : "memory");
    }

    // (h5) decoder output projection (PRE-update h = a[2..9]) -- after publish
    if (dec && w < 2) {
      f32x4 ao; ao[0] = bo; ao[1] = bo; ao[2] = bo; ao[3] = bo;
#pragma unroll
      for (int kt = 0; kt < 8; ++kt)
        ao = __builtin_amdgcn_mfma_f32_16x16x32_f16(a[2 + kt], woutLds[(w * 8 + kt) * 64 + lane], ao, 0, 0, 0);
      int tpos = 2047 - t;
      int f = q * 32 + w * 16 + n16;
#pragma unroll
      for (int r = 0; r < 4; ++r) {
        int m = quad * 4 + r;
        out[((size_t)(b0 + m) * Tt + tpos) * Ff + f] = ao[r];
      }
    }
  }
}

extern "C" void kernel_launch(void* const* d_in, const int* in_sizes, int n_in,
                              void* d_out, int out_size, void* d_ws, size_t ws_size,
                              hipStream_t stream) {
  const float* ts  = (const float*)d_in[0];
  const float* Wie = (const float*)d_in[1];
  const float* Whe = (const float*)d_in[2];
  const float* be  = (const float*)d_in[3];
  const float* Wid = (const float*)d_in[4];
  const float* Whd = (const float*)d_in[5];
  const float* bd  = (const float*)d_in[6];
  const float* Wo  = (const float*)d_in[7];
  const float* bo  = (const float*)d_in[8];

  h16* ws16 = (h16*)d_ws;
  unsigned int* flags = (unsigned int*)((char*)d_ws + FLAGS_BYTE_OFF);
  u64* tagbuf = (u64*)((char*)d_ws + TAGHB_BYTE_OFF);
  float* out = (float*)d_out;

  // total ws use: ~1.47 MB + 256 KB tagged h = ~1.74 MB
  lstm_prep<<<2624, 256, 0, stream>>>(Wie, Whe, Wid, Whd, Wo, ws16, flags);
  lstm_main<<<16, 256, 0, stream>>>(ts, be, bd, bo, ws16, tagbuf, out);
}